// Round 1
// baseline (42.732 us; speedup 1.0000x reference)
//
#include <hip/hip_runtime.h>

#define L 512
#define LMASK 511
#define HID 32

constexpr int ROWS_PER_BLOCK = 8;
constexpr int BLOCKS_PER_B   = L / ROWS_PER_BLOCK;      // 64
constexpr int THREADS        = 256;
constexpr int SITES_PER_THREAD = ROWS_PER_BLOCK * L / THREADS; // 16

// Stage 1: per-site stencil + MLP, per-block partial sums into d_ws.
__global__ __launch_bounds__(THREADS)
void site_kernel(const float* __restrict__ x,
                 const float* __restrict__ W1,
                 const float* __restrict__ b1,
                 const float* __restrict__ W2,
                 float* __restrict__ partial) {
    const float K = 2.8853900817779268f;   // 2*log2(e)

    // Pre-scaled weights in registers (uniform loads; h-loop compile-time).
    float wa[HID], wb[HID], wc[HID], w0[HID], w2[HID];
#pragma unroll
    for (int h = 0; h < HID; ++h) {
        wa[h] = K * W1[h * 3 + 0];
        wb[h] = K * W1[h * 3 + 1];
        wc[h] = K * W1[h * 3 + 2];
        w0[h] = K * b1[h];
        w2[h] = -2.0f * W2[h];             // fold tanh = 1 - 2r; const part in reduce
    }

    const int blk = blockIdx.x;
    const int b  = blk >> 6;               // blk / BLOCKS_PER_B
    const int r0 = (blk & (BLOCKS_PER_B - 1)) * ROWS_PER_BLOCK;
    const float* __restrict__ xb = x + (size_t)b * (L * L);

    const int t = threadIdx.x;
    float acc = 0.0f;

#pragma unroll 2
    for (int it = 0; it < SITES_PER_THREAD; ++it) {
        const int s  = t + it * THREADS;
        const int i  = r0 + (s >> 9);
        const int j  = s & LMASK;
        const int im = (i + LMASK) & LMASK;
        const int ip = (i + 1) & LMASK;
        const int jm = (j + LMASK) & LMASK;
        const int jp = (j + 1) & LMASK;

        const float c   = xb[i  * L + j];
        const float u   = xb[im * L + j];
        const float d   = xb[ip * L + j];
        const float lf  = xb[i  * L + jm];
        const float rg  = xb[i  * L + jp];

        const float lr = lf + rg;          // == sx
        const float x1 = lr + u + d;       // 4-neighbor sum
        const float f0 = c * c;
        const float f1 = x1 * c;
        const float f2 = lr * c;

#pragma unroll
        for (int h = 0; h < HID; ++h) {
            // z' = 2*log2e*(W1.f + b1) via pre-scaled weights
            const float z = fmaf(f0, wa[h], fmaf(f1, wb[h], fmaf(f2, wc[h], w0[h])));
            const float e = __builtin_amdgcn_exp2f(z);
            const float r = __builtin_amdgcn_rcpf(1.0f + e);
            acc = fmaf(w2[h], r, acc);     // acc += -2*W2[h]*r
        }
    }

    // wave reduce (64 lanes), then cross-wave via LDS
#pragma unroll
    for (int off = 32; off > 0; off >>= 1)
        acc += __shfl_down(acc, off, 64);

    __shared__ float wsum[THREADS / 64];
    const int wid = t >> 6, lane = t & 63;
    if (lane == 0) wsum[wid] = acc;
    __syncthreads();
    if (t == 0)
        partial[blk] = wsum[0] + wsum[1] + wsum[2] + wsum[3];
}

// Stage 2: deterministic fixed-order reduction + folded tanh constant.
__global__ __launch_bounds__(64)
void reduce_kernel(const float* __restrict__ partial,
                   const float* __restrict__ W2,
                   const float* __restrict__ b2,
                   float* __restrict__ out) {
    const int b = blockIdx.x, t = threadIdx.x;
    const float NS = (float)(L * L);       // 262144 sites per config

    float v = partial[b * BLOCKS_PER_B + t];
    if (t < HID) v += NS * W2[t];          // + L^2 * sum_h W2[h]
    if (t == 0)  v += NS * b2[0];          // + L^2 * b2

#pragma unroll
    for (int off = 32; off > 0; off >>= 1)
        v += __shfl_down(v, off, 64);

    if (t == 0) out[b] = v;
}

extern "C" void kernel_launch(void* const* d_in, const int* in_sizes, int n_in,
                              void* d_out, int out_size, void* d_ws, size_t ws_size,
                              hipStream_t stream) {
    const float* x  = (const float*)d_in[0];
    const float* W1 = (const float*)d_in[1];
    const float* b1 = (const float*)d_in[2];
    const float* W2 = (const float*)d_in[3];
    const float* b2 = (const float*)d_in[4];
    float* out      = (float*)d_out;
    float* partial  = (float*)d_ws;        // B * BLOCKS_PER_B floats (4 KiB)

    const int B = in_sizes[0] / (L * L);   // 16

    site_kernel<<<B * BLOCKS_PER_B, THREADS, 0, stream>>>(x, W1, b1, W2, partial);
    reduce_kernel<<<B, 64, 0, stream>>>(partial, W2, b2, out);
}

// Round 2
// 42.090 us; speedup vs baseline: 1.0152x; 1.0152x over previous
//
#include <hip/hip_runtime.h>

#define L 512
#define LMASK 511
#define HID 32

constexpr int THREADS = 256;
constexpr int ROWS_PER_BLOCK = 8;
constexpr int BLOCKS_PER_B   = L / ROWS_PER_BLOCK;      // 64

// Stage 1: per-site stencil + MLP, per-block partial sums into d_ws.
__global__ __launch_bounds__(THREADS)
void site_kernel(const float* __restrict__ x,
                 const float* __restrict__ W1,
                 const float* __restrict__ b1,
                 const float* __restrict__ W2,
                 float* __restrict__ partial) {
    const float K = 2.8853900817779268f;   // 2*log2(e)

    // Pre-scaled weights (wave-uniform; compiler keeps in SGPR/VGPR).
    float wa[HID], wb[HID], wc[HID], w0[HID], w2[HID];
#pragma unroll
    for (int h = 0; h < HID; ++h) {
        wa[h] = K * W1[h * 3 + 0];
        wb[h] = K * W1[h * 3 + 1];
        wc[h] = K * W1[h * 3 + 2];
        w0[h] = K * b1[h];
        w2[h] = -2.0f * W2[h];             // tanh = 1 - 2r; const part in reduce
    }

    const int blk = blockIdx.x;
    const int b   = blk >> 6;
    const int r0  = (blk & (BLOCKS_PER_B - 1)) * ROWS_PER_BLOCK;
    const float* __restrict__ xb = x + (size_t)b * (L * L);

    const int t   = threadIdx.x;
    const int j0  = t, j1 = t + THREADS;
    const int j0m = (j0 + LMASK) & LMASK, j0p = (j0 + 1) & LMASK;
    const int j1m = (j1 + LMASK) & LMASK, j1p = (j1 + 1) & LMASK;

    float acc0 = 0.0f, acc1 = 0.0f;

    // One site's stencil + MLP (pair-grouped rcp amortization).
    auto process = [&](float c, float u, float d, float lf, float rg) {
        const float lr = lf + rg;                  // == sx
        const float x1 = lr + u + d;               // 4-neighbor sum
        float f0 = c * c;
        float f1 = x1 * c;
        float f2 = lr * c;
        // Safety rescale: bound sum|f| <= 50 so |z'|<=60, pair products <2^120.
        // Activates only at astronomically rare sites (tanh saturated anyway).
        const float m = f0 + fabsf(f1) + fabsf(f2);
        const float s = fminf(1.0f, 50.0f * __builtin_amdgcn_rcpf(m));
        f0 *= s; f1 *= s; f2 *= s;
#pragma unroll
        for (int h = 0; h < HID; h += 2) {
            const float z1 = fmaf(f0, wa[h],   fmaf(f1, wb[h],   fmaf(f2, wc[h],   w0[h])));
            const float z2 = fmaf(f0, wa[h+1], fmaf(f1, wb[h+1], fmaf(f2, wc[h+1], w0[h+1])));
            const float d1 = 1.0f + __builtin_amdgcn_exp2f(z1);
            const float d2 = 1.0f + __builtin_amdgcn_exp2f(z2);
            const float p  = d1 * d2;
            const float un = fmaf(w2[h+1], d1, w2[h] * d2);
            const float rr = __builtin_amdgcn_rcpf(p);
            if (h & 2) acc1 = fmaf(un, rr, acc1);
            else       acc0 = fmaf(un, rr, acc0);
        }
    };

    // Software-pipelined over rows: prefetch next row's 10 loads before
    // the current row's two h-loops (~1600 busy cycles hides L1/L2 latency).
    float cA,uA,dA,lA,rA, cB,uB,dB,lB,rB;
    {
        const int i = r0, im = (i + LMASK) & LMASK, ip = (i + 1) & LMASK;
        const float* rc = xb + i  * L;
        const float* ru = xb + im * L;
        const float* rd = xb + ip * L;
        cA = rc[j0]; uA = ru[j0]; dA = rd[j0]; lA = rc[j0m]; rA = rc[j0p];
        cB = rc[j1]; uB = ru[j1]; dB = rd[j1]; lB = rc[j1m]; rB = rc[j1p];
    }

#pragma unroll
    for (int r = 0; r < ROWS_PER_BLOCK; ++r) {
        float nA0=0,nA1=0,nA2=0,nA3=0,nA4=0, nB0=0,nB1=0,nB2=0,nB3=0,nB4=0;
        if (r + 1 < ROWS_PER_BLOCK) {
            const int i = r0 + r + 1, im = (i + LMASK) & LMASK, ip = (i + 1) & LMASK;
            const float* rc = xb + i  * L;
            const float* ru = xb + im * L;
            const float* rd = xb + ip * L;
            nA0 = rc[j0]; nA1 = ru[j0]; nA2 = rd[j0]; nA3 = rc[j0m]; nA4 = rc[j0p];
            nB0 = rc[j1]; nB1 = ru[j1]; nB2 = rd[j1]; nB3 = rc[j1m]; nB4 = rc[j1p];
        }
        process(cA, uA, dA, lA, rA);
        process(cB, uB, dB, lB, rB);
        if (r + 1 < ROWS_PER_BLOCK) {
            cA=nA0; uA=nA1; dA=nA2; lA=nA3; rA=nA4;
            cB=nB0; uB=nB1; dB=nB2; lB=nB3; rB=nB4;
        }
    }

    float acc = acc0 + acc1;

    // wave reduce (64 lanes), then cross-wave via LDS
#pragma unroll
    for (int off = 32; off > 0; off >>= 1)
        acc += __shfl_down(acc, off, 64);

    __shared__ float wsum[THREADS / 64];
    const int wid = t >> 6, lane = t & 63;
    if (lane == 0) wsum[wid] = acc;
    __syncthreads();
    if (t == 0)
        partial[blk] = wsum[0] + wsum[1] + wsum[2] + wsum[3];
}

// Stage 2: deterministic fixed-order reduction + folded tanh constant.
__global__ __launch_bounds__(64)
void reduce_kernel(const float* __restrict__ partial,
                   const float* __restrict__ W2,
                   const float* __restrict__ b2,
                   float* __restrict__ out) {
    const int b = blockIdx.x, t = threadIdx.x;
    const float NS = (float)(L * L);       // 262144 sites per config

    float v = partial[b * BLOCKS_PER_B + t];
    if (t < HID) v += NS * W2[t];          // + L^2 * sum_h W2[h]
    if (t == 0)  v += NS * b2[0];          // + L^2 * b2

#pragma unroll
    for (int off = 32; off > 0; off >>= 1)
        v += __shfl_down(v, off, 64);

    if (t == 0) out[b] = v;
}

extern "C" void kernel_launch(void* const* d_in, const int* in_sizes, int n_in,
                              void* d_out, int out_size, void* d_ws, size_t ws_size,
                              hipStream_t stream) {
    const float* x  = (const float*)d_in[0];
    const float* W1 = (const float*)d_in[1];
    const float* b1 = (const float*)d_in[2];
    const float* W2 = (const float*)d_in[3];
    const float* b2 = (const float*)d_in[4];
    float* out      = (float*)d_out;
    float* partial  = (float*)d_ws;        // B * BLOCKS_PER_B floats (4 KiB)

    const int B = in_sizes[0] / (L * L);   // 16

    site_kernel<<<B * BLOCKS_PER_B, THREADS, 0, stream>>>(x, W1, b1, W2, partial);
    reduce_kernel<<<B, 64, 0, stream>>>(partial, W2, b2, out);
}